// Round 1
// baseline (335.787 us; speedup 1.0000x reference)
//
#include <hip/hip_runtime.h>
#include <hip/hip_bf16.h>

typedef __attribute__((ext_vector_type(8))) short bf16x8;
typedef __attribute__((ext_vector_type(4))) float f32x4;

__device__ __forceinline__ float b2f(unsigned short u) {
  union { unsigned int i; float f; } x; x.i = ((unsigned int)u) << 16; return x.f;
}
__device__ __forceinline__ unsigned short f2b(float f) {
  union { __hip_bfloat16 h; unsigned short u; } x; x.h = __float2bfloat16(f); return x.u;
}
__device__ __forceinline__ f32x4 mfma16(bf16x8 a, bf16x8 b, f32x4 c) {
  return __builtin_amdgcn_mfma_f32_16x16x32_bf16(a, b, c, 0, 0, 0);
}
__device__ __forceinline__ void gl16(const void* g, void* l) {
  __builtin_amdgcn_global_load_lds(
      (const __attribute__((address_space(1))) unsigned int*)g,
      (__attribute__((address_space(3))) unsigned int*)l, 16, 0, 0);
}

// ---------------- cast f32 -> bf16 (vectorized) ----------------
__global__ __launch_bounds__(256) void cast_k(const float* __restrict__ src,
                                              unsigned short* __restrict__ dst, int n4) {
  int i = blockIdx.x * 256 + threadIdx.x;
  if (i >= n4) return;
  float4 v = ((const float4*)src)[i];
  ushort4 o;
  o.x = f2b(v.x); o.y = f2b(v.y); o.z = f2b(v.z); o.w = f2b(v.w);
  ((ushort4*)dst)[i] = o;
}

// ---------------- generic 128x128 bf16 GEMM: C = A * W^T ----------------
// MODE 0: f32 out + bias (final projection)
// MODE 1: QKV fused (N=3072): per-1024 column block -> {Wq,Wk,Wv}, bias, elu+1 on q,k; bf16 out
template<int MODE>
__global__ __launch_bounds__(256) void gemm128(
    const unsigned short* __restrict__ A,
    const unsigned short* __restrict__ W0, const unsigned short* __restrict__ W1,
    const unsigned short* __restrict__ W2,
    const float* __restrict__ bias0, const float* __restrict__ bias1, const float* __restrict__ bias2,
    float* __restrict__ outF,
    unsigned short* __restrict__ o0, unsigned short* __restrict__ o1, unsigned short* __restrict__ o2,
    int M, int N, int K, int tiles_m)
{
  __shared__ unsigned short As[128 * 32];
  __shared__ unsigned short Bs[128 * 32];
  const int nwg = gridDim.x;
  int bid = blockIdx.x;
  int cpx = nwg >> 3;                       // nwg % 8 == 0 for all our launches
  int sbid = (bid & 7) * cpx + (bid >> 3);  // XCD-aware swizzle (bijective)
  int tm = sbid % tiles_m, tn = sbid / tiles_m;
  int m0 = tm * 128, n0 = tn * 128;

  const unsigned short* W = W0; const float* bias = bias0; unsigned short* outB = o0;
  int sel = 0;
  if (MODE == 1) {
    sel = n0 >> 10;
    if (sel == 1) { W = W1; bias = bias1; outB = o1; }
    else if (sel == 2) { W = W2; bias = bias2; outB = o2; }
  }
  int nloc0 = (MODE == 1) ? (n0 & 1023) : n0;

  int t = threadIdx.x, w = t >> 6, l = t & 63;
  int wm = w >> 1, wn = w & 1;

  // staging: granule G -> (row = G>>2, slot = G&3); source k-granule = slot ^ ((row>>1)&3)
  int G0 = (w * 2 + 0) * 64 + l, G1 = (w * 2 + 1) * 64 + l;
  int r0 = G0 >> 2, r1 = G1 >> 2;
  int g0 = (G0 & 3) ^ ((r0 >> 1) & 3);
  int g1 = (G1 & 3) ^ ((r1 >> 1) & 3);
  const unsigned short* gA0 = A + (size_t)(m0 + r0) * K + g0 * 8;
  const unsigned short* gA1 = A + (size_t)(m0 + r1) * K + g1 * 8;
  const unsigned short* gB0 = W + (size_t)(nloc0 + r0) * K + g0 * 8;
  const unsigned short* gB1 = W + (size_t)(nloc0 + r1) * K + g1 * 8;
  char* lA0 = (char*)As + (w * 2 + 0) * 1024;
  char* lA1 = (char*)As + (w * 2 + 1) * 1024;
  char* lB0 = (char*)Bs + (w * 2 + 0) * 1024;
  char* lB1 = (char*)Bs + (w * 2 + 1) * 1024;

  int swzl = ((l & 15) >> 1) & 3;
  int colb = ((l >> 4) ^ swzl) * 16;  // conflict-free swizzled read column (bytes)
  const char* Ard = (const char*)As + (wm * 64 + (l & 15)) * 64 + colb;
  const char* Brd = (const char*)Bs + (wn * 64 + (l & 15)) * 64 + colb;

  f32x4 acc[4][4];
  f32x4 zero = {0.f, 0.f, 0.f, 0.f};
#pragma unroll
  for (int i = 0; i < 4; ++i)
#pragma unroll
    for (int j = 0; j < 4; ++j) acc[i][j] = zero;

  int nk = K >> 5;
  for (int kt = 0; kt < nk; ++kt) {
    gl16(gA0 + kt * 32, lA0);
    gl16(gA1 + kt * 32, lA1);
    gl16(gB0 + kt * 32, lB0);
    gl16(gB1 + kt * 32, lB1);
    __syncthreads();
    bf16x8 af[4], bfr[4];
#pragma unroll
    for (int mi = 0; mi < 4; ++mi) af[mi] = *(const bf16x8*)(Ard + mi * 1024);
#pragma unroll
    for (int ni = 0; ni < 4; ++ni) bfr[ni] = *(const bf16x8*)(Brd + ni * 1024);
#pragma unroll
    for (int mi = 0; mi < 4; ++mi)
#pragma unroll
      for (int ni = 0; ni < 4; ++ni)
        acc[mi][ni] = mfma16(af[mi], bfr[ni], acc[mi][ni]);
    __syncthreads();
  }

#pragma unroll
  for (int mi = 0; mi < 4; ++mi) {
#pragma unroll
    for (int ni = 0; ni < 4; ++ni) {
      int gc = n0 + wn * 64 + ni * 16 + (l & 15);
      int gr0 = m0 + wm * 64 + mi * 16 + ((l >> 4) << 2);
      f32x4 a = acc[mi][ni];
      if (MODE == 0) {
        float bb = bias[gc];
#pragma unroll
        for (int r = 0; r < 4; ++r) outF[(size_t)(gr0 + r) * N + gc] = a[r] + bb;
      } else {
        int c = gc & 1023;
        float bb = bias[c];
#pragma unroll
        for (int r = 0; r < 4; ++r) {
          float v = a[r] + bb;
          if (sel < 2) v = (v > 0.0f) ? (v + 1.0f) : __expf(v);  // elu(x)+1
          outB[(size_t)(gr0 + r) * 1024 + c] = f2b(v);
        }
      }
    }
  }
}

// ---------------- per-head transpose: (b,n,h,d) -> [bh][d][n], optional k_sum ----------------
template<int DOSUM>
__global__ __launch_bounds__(256) void transpose_hd(
    const unsigned short* __restrict__ in,   // (16384, 1024)
    unsigned short* __restrict__ out,        // [64][64][4096]
    float* __restrict__ ksum)                // [64][64]
{
  int bid = blockIdx.x;
  int bh = bid >> 6, nt = bid & 63;
  int b = bh >> 4, h = bh & 15;
  int n0 = nt << 6;
  __shared__ unsigned short lds[64][72];
  int t = threadIdx.x;
  int rr = t >> 3, cc = (t & 7) << 3;
#pragma unroll
  for (int p = 0; p < 2; ++p) {
    int n = rr + p * 32;
    const unsigned short* src = in + ((size_t)(b * 4096 + n0 + n) * 1024 + h * 64 + cc);
    *(bf16x8*)&lds[n][cc] = *(const bf16x8*)src;
  }
  __syncthreads();
#pragma unroll
  for (int p = 0; p < 2; ++p) {
    int d = rr + p * 32;
    union { bf16x8 v; unsigned short u[8]; } pk;
    float s = 0.f;
#pragma unroll
    for (int j = 0; j < 8; ++j) {
      unsigned short uv = lds[cc + j][d];
      pk.u[j] = uv;
      if (DOSUM) s += b2f(uv);
    }
    *(bf16x8*)(out + ((size_t)bh * 64 + d) * 4096 + n0 + cc) = pk.v;
    if (DOSUM) {
      s += __shfl_xor(s, 1);
      s += __shfl_xor(s, 2);
      s += __shfl_xor(s, 4);
      if ((t & 7) == 0) atomicAdd(ksum + bh * 64 + d, s);
    }
  }
}

// ---------------- context: ctxT[bh][e][d] = sum_n v[n,e]*k[n,d], split-K over n ----------------
__global__ __launch_bounds__(64) void ctx_gemm(
    const unsigned short* __restrict__ vT,  // [bh][64][4096]
    const unsigned short* __restrict__ kT,  // [bh][64][4096]
    float* __restrict__ ctxT)               // [bh][64][64]
{
  int bid = blockIdx.x;
  int bh = bid >> 3, ch = bid & 7;
  int l = threadIdx.x;
  const unsigned short* aB = vT + ((size_t)bh * 64 + (l & 15)) * 4096 + ch * 512 + ((l >> 4) << 3);
  const unsigned short* bB = kT + ((size_t)bh * 64 + (l & 15)) * 4096 + ch * 512 + ((l >> 4) << 3);
  f32x4 acc[4][4];
  f32x4 zero = {0.f, 0.f, 0.f, 0.f};
#pragma unroll
  for (int i = 0; i < 4; ++i)
#pragma unroll
    for (int j = 0; j < 4; ++j) acc[i][j] = zero;
  for (int ks = 0; ks < 16; ++ks) {
    bf16x8 av[4], bv[4];
#pragma unroll
    for (int mi = 0; mi < 4; ++mi) av[mi] = *(const bf16x8*)(aB + (size_t)mi * 16 * 4096 + ks * 32);
#pragma unroll
    for (int ni = 0; ni < 4; ++ni) bv[ni] = *(const bf16x8*)(bB + (size_t)ni * 16 * 4096 + ks * 32);
#pragma unroll
    for (int mi = 0; mi < 4; ++mi)
#pragma unroll
      for (int ni = 0; ni < 4; ++ni)
        acc[mi][ni] = mfma16(av[mi], bv[ni], acc[mi][ni]);
  }
#pragma unroll
  for (int mi = 0; mi < 4; ++mi)
#pragma unroll
    for (int ni = 0; ni < 4; ++ni)
#pragma unroll
      for (int r = 0; r < 4; ++r) {
        int e = mi * 16 + ((l >> 4) << 2) + r;
        int d = ni * 16 + (l & 15);
        atomicAdd(ctxT + (size_t)bh * 4096 + e * 64 + d, acc[mi][ni][r]);
      }
}

// ---------------- D_inv = 1/(q . k_sum + eps) ----------------
__global__ __launch_bounds__(256) void denom_k(
    const unsigned short* __restrict__ q,
    const float* __restrict__ ksum,
    float* __restrict__ dinv)
{
  int t = threadIdx.x, w = t >> 6, l = t & 63;
  int idx = blockIdx.x * 4 + w;
  int b = idx >> 12;
  int h = l >> 2, part = l & 3;
  const unsigned short* qp = q + (size_t)idx * 1024 + h * 64 + part * 16;
  const float* kp = ksum + ((b << 4) + h) * 64 + part * 16;
  bf16x8 v0 = *(const bf16x8*)qp;
  bf16x8 v1 = *(const bf16x8*)(qp + 8);
  float s = 0.f;
#pragma unroll
  for (int j = 0; j < 8; ++j) s += b2f((unsigned short)v0[j]) * kp[j];
#pragma unroll
  for (int j = 0; j < 8; ++j) s += b2f((unsigned short)v1[j]) * kp[8 + j];
  s += __shfl_xor(s, 1);
  s += __shfl_xor(s, 2);
  if (part == 0) dinv[(size_t)idx * 16 + h] = 1.0f / (s + 1e-6f);
}

// ---------------- att = (q @ ctx) * D_inv, written in-place into q ----------------
__global__ __launch_bounds__(256) void att_gemm(
    unsigned short* __restrict__ q,      // (16384,1024) in/out
    const float* __restrict__ ctxT,      // [bh][e][d]
    const float* __restrict__ dinv)      // [16384][16]
{
  int bid = blockIdx.x;
  int bh = bid & 63, mt = bid >> 6;
  int b = bh >> 4, h = bh & 15;
  int t = threadIdx.x, w = t >> 6, l = t & 63;
  int m0 = mt * 256 + w * 64;

  bf16x8 bfr[2][4];
  const float* cb = ctxT + (size_t)bh * 4096;
#pragma unroll
  for (int ks = 0; ks < 2; ++ks)
#pragma unroll
    for (int ni = 0; ni < 4; ++ni) {
      const float* p = cb + (ni * 16 + (l & 15)) * 64 + ks * 32 + ((l >> 4) << 3);
#pragma unroll
      for (int j = 0; j < 8; ++j) bfr[ks][ni][j] = (short)f2b(p[j]);
    }

  f32x4 acc[4][4];
  f32x4 zero = {0.f, 0.f, 0.f, 0.f};
#pragma unroll
  for (int i = 0; i < 4; ++i)
#pragma unroll
    for (int j = 0; j < 4; ++j) acc[i][j] = zero;

  size_t rowbase = (size_t)(b * 4096 + m0 + (l & 15)) * 1024 + h * 64 + ((l >> 4) << 3);
#pragma unroll
  for (int mi = 0; mi < 4; ++mi) {
#pragma unroll
    for (int ks = 0; ks < 2; ++ks) {
      bf16x8 av = *(const bf16x8*)(q + rowbase + (size_t)mi * 16 * 1024 + ks * 32);
#pragma unroll
      for (int ni = 0; ni < 4; ++ni) acc[mi][ni] = mfma16(av, bfr[ks][ni], acc[mi][ni]);
    }
  }

#pragma unroll
  for (int mi = 0; mi < 4; ++mi)
#pragma unroll
    for (int ni = 0; ni < 4; ++ni) {
      int e = ni * 16 + (l & 15);
#pragma unroll
      for (int r = 0; r < 4; ++r) {
        int npos = m0 + mi * 16 + ((l >> 4) << 2) + r;
        float sc = dinv[(size_t)(b * 4096 + npos) * 16 + h];
        q[(size_t)(b * 4096 + npos) * 1024 + h * 64 + e] = f2b(acc[mi][ni][r] * sc);
      }
    }
}

extern "C" void kernel_launch(void* const* d_in, const int* in_sizes, int n_in,
                              void* d_out, int out_size, void* d_ws, size_t ws_size,
                              hipStream_t stream)
{
  const float* x  = (const float*)d_in[0];
  const float* Wq = (const float*)d_in[1];
  const float* bq = (const float*)d_in[2];
  const float* Wk = (const float*)d_in[3];
  const float* bk = (const float*)d_in[4];
  const float* Wv = (const float*)d_in[5];
  const float* bv = (const float*)d_in[6];
  const float* Wo = (const float*)d_in[7];
  const float* bo = (const float*)d_in[8];
  float* out = (float*)d_out;

  char* ws = (char*)d_ws;
  const size_t SB = (size_t)16384 * 1024 * 2;  // 32 MiB slab
  const size_t NEED = 4 * SB + 4 * (1u << 21) + 2 * (1u << 20) + (1u << 14);
  if (ws_size < NEED) return;  // signature: absmax == max|ref| ~ 6.4e-2

  unsigned short* xb  = (unsigned short*)(ws);           // x bf16; later vT
  unsigned short* qb  = (unsigned short*)(ws + SB);      // q bf16; later att
  unsigned short* kb  = (unsigned short*)(ws + 2 * SB);  // k bf16
  unsigned short* vb  = (unsigned short*)(ws + 3 * SB);  // v bf16; later kT
  unsigned short* wqb = (unsigned short*)(ws + 4 * SB);
  unsigned short* wkb = (unsigned short*)(ws + 4 * SB + (1u << 21));
  unsigned short* wvb = (unsigned short*)(ws + 4 * SB + (2u << 21));
  unsigned short* wob = (unsigned short*)(ws + 4 * SB + (3u << 21));
  float* ctxT = (float*)(ws + 4 * SB + (4u << 21));
  float* dinv = (float*)(ws + 4 * SB + (4u << 21) + (1u << 20));
  float* ksum = (float*)(ws + 4 * SB + (4u << 21) + (2u << 20));

  hipMemsetAsync(ctxT, 0, 64 * 64 * 64 * 4, stream);
  hipMemsetAsync(ksum, 0, 64 * 64 * 4, stream);

  cast_k<<<16384, 256, 0, stream>>>(x, xb, 16777216 / 4);
  cast_k<<<1024, 256, 0, stream>>>(Wq, wqb, 1048576 / 4);
  cast_k<<<1024, 256, 0, stream>>>(Wk, wkb, 1048576 / 4);
  cast_k<<<1024, 256, 0, stream>>>(Wv, wvb, 1048576 / 4);
  cast_k<<<1024, 256, 0, stream>>>(Wo, wob, 1048576 / 4);

  // QKV: (16384 x 1024) @ (3072 x 1024)^T, fused bias + elu+1 on q,k
  gemm128<1><<<3072, 256, 0, stream>>>(xb, wqb, wkb, wvb, bq, bk, bv,
                                       nullptr, qb, kb, vb, 16384, 3072, 1024, 128);

  transpose_hd<0><<<4096, 256, 0, stream>>>(vb, xb, nullptr);  // vT -> xb
  transpose_hd<1><<<4096, 256, 0, stream>>>(kb, vb, ksum);     // kT -> vb, k_sum

  ctx_gemm<<<512, 64, 0, stream>>>(xb, vb, ctxT);

  denom_k<<<4096, 256, 0, stream>>>(qb, ksum, dinv);

  att_gemm<<<1024, 256, 0, stream>>>(qb, ctxT, dinv);          // att -> qb (in place)

  // final: att @ Wo^T + bo -> f32 out
  gemm128<0><<<1024, 256, 0, stream>>>(qb, wob, nullptr, nullptr, bo, nullptr, nullptr,
                                       out, nullptr, nullptr, nullptr, 16384, 1024, 1024, 128);
}

// Round 4
// 276.309 us; speedup vs baseline: 1.2153x; 1.2153x over previous
//
#include <hip/hip_runtime.h>
#include <hip/hip_bf16.h>

typedef __attribute__((ext_vector_type(8))) short bf16x8;
typedef __attribute__((ext_vector_type(4))) float f32x4;

__device__ __forceinline__ float b2f(unsigned short u) {
  union { unsigned int i; float f; } x; x.i = ((unsigned int)u) << 16; return x.f;
}
__device__ __forceinline__ unsigned short f2b(float f) {
  union { __hip_bfloat16 h; unsigned short u; } x; x.h = __float2bfloat16(f); return x.u;
}
__device__ __forceinline__ f32x4 mfma16(bf16x8 a, bf16x8 b, f32x4 c) {
  return __builtin_amdgcn_mfma_f32_16x16x32_bf16(a, b, c, 0, 0, 0);
}
__device__ __forceinline__ void gl16(const void* g, void* l) {
  __builtin_amdgcn_global_load_lds(
      (const __attribute__((address_space(1))) unsigned int*)g,
      (__attribute__((address_space(3))) unsigned int*)l, 16, 0, 0);
}

// ---------------- cast f32 -> bf16 (vectorized) ----------------
__global__ __launch_bounds__(256) void cast_k(const float* __restrict__ src,
                                              unsigned short* __restrict__ dst, int n4) {
  int i = blockIdx.x * 256 + threadIdx.x;
  if (i >= n4) return;
  float4 v = ((const float4*)src)[i];
  ushort4 o;
  o.x = f2b(v.x); o.y = f2b(v.y); o.z = f2b(v.z); o.w = f2b(v.w);
  ((ushort4*)dst)[i] = o;
}

// =============== 256x256 8-phase bf16 GEMM (C = A * W^T), K=1024 ===============
// MODE 0: f32 out + bias (final projection, N=1024)
// MODE 1: QKV fused (N=3072): per-1024 column block -> {Wq,Wk,Wv}, bias, elu+1 on q,k
//
// 8 waves (2M x 4N), per-wave output 128x64. BK=64. LDS 128KiB:
//   A: [buf][granule][128 rows][128B]   granule g = rows with bit6==g  (m-half)
//   B: same with bit5 (n-half), base +65536.
// LDS row lr is swizzled: 16B slot' = slot ^ (lr&7); staged via pre-swizzled
// global source (involution), read with the same XOR.
// Stage ledger (steady state, iter j computes tiles 2j,2j+1 from buf0,buf1):
//   ph1: A-g1(t 2j+1,buf1)  ph2: B-g1(2j+1,buf1)  ph3: A-g0(2j+2,buf0)
//   ph4: B-g0(2j+2,buf0)    ph5: A-g1(2j+2,buf0)  ph6: B-g1(2j+2,buf0)
//   ph7: A-g0(2j+3,buf1)    ph8: B-g0(2j+3,buf1)
// Each stage target's last reader drains >=1 phase earlier (lgkmcnt(0) before
// MFMA + trailing barrier). vmcnt(4) at ph4 covers buf1 reads of ph5-8
// (outstanding = ph3,ph4 stages); vmcnt(4) at ph8 covers buf0 reads of next
// ph1-4 (outstanding = ph7,ph8). Never vmcnt(0) in the loop; vmcnt(0) once
// after the loop so no global_load_lds is in flight at s_endpgm.
// Last iter re-stages tiles 14/15 (identical bytes, L2-hot) instead of
// wrapping to cold tiles 0/1.
#define BARX() asm volatile("s_barrier" ::: "memory")
#define LGKM0() asm volatile("s_waitcnt lgkmcnt(0)" ::: "memory")
#define WAITV4() asm volatile("s_waitcnt vmcnt(4)" ::: "memory")
#define WAITV0() asm volatile("s_waitcnt vmcnt(0)" ::: "memory")
#define P1() __builtin_amdgcn_s_setprio(1)
#define P0() __builtin_amdgcn_s_setprio(0)

#define STAGE_A(BUF, G, TAU) do { \
  gl16(gA_0 + (size_t)(G) * 65536 + (TAU) * 64, sAB + (BUF) * 32768 + (G) * 16384 + u0 * 16); \
  gl16(gA_1 + (size_t)(G) * 65536 + (TAU) * 64, sAB + (BUF) * 32768 + (G) * 16384 + u1 * 16); } while (0)
#define STAGE_B(BUF, G, TAU) do { \
  gl16(gB_0 + (size_t)(G) * 32768 + (TAU) * 64, sAB + 65536 + (BUF) * 32768 + (G) * 16384 + u0 * 16); \
  gl16(gB_1 + (size_t)(G) * 32768 + (TAU) * 64, sAB + 65536 + (BUF) * 32768 + (G) * 16384 + u1 * 16); } while (0)

#define LOAD_A(BUF, MH) do { \
  _Pragma("unroll") for (int mi = 0; mi < 4; ++mi) { \
    const char* p_ = (const char*)sAB + (BUF) * 32768 + (MH) * 16384 + aRd + mi * 2048; \
    af[mi][0] = *(const bf16x8*)(p_ + sr0); \
    af[mi][1] = *(const bf16x8*)(p_ + sr1); } } while (0)
#define LOAD_B(BUF, NH, DST) do { \
  _Pragma("unroll") for (int ni = 0; ni < 2; ++ni) { \
    const char* p_ = (const char*)sAB + 65536 + (BUF) * 32768 + (NH) * 16384 + bRd + ni * 2048; \
    DST[ni][0] = *(const bf16x8*)(p_ + sr0); \
    DST[ni][1] = *(const bf16x8*)(p_ + sr1); } } while (0)

#define QUAD(MH, NH, BF) do { \
  _Pragma("unroll") for (int mi = 0; mi < 4; ++mi) \
    _Pragma("unroll") for (int ni = 0; ni < 2; ++ni) { \
      acc[(MH) * 4 + mi][(NH) * 2 + ni] = mfma16(af[mi][0], BF[ni][0], acc[(MH) * 4 + mi][(NH) * 2 + ni]); \
      acc[(MH) * 4 + mi][(NH) * 2 + ni] = mfma16(af[mi][1], BF[ni][1], acc[(MH) * 4 + mi][(NH) * 2 + ni]); } } while (0)

template<int MODE>
__global__ __launch_bounds__(512, 2) void gemm256(
    const unsigned short* __restrict__ A,
    const unsigned short* __restrict__ W0, const unsigned short* __restrict__ W1,
    const unsigned short* __restrict__ W2,
    const float* __restrict__ bias0, const float* __restrict__ bias1, const float* __restrict__ bias2,
    float* __restrict__ outF,
    unsigned short* __restrict__ o0, unsigned short* __restrict__ o1, unsigned short* __restrict__ o2,
    int tiles_m)
{
  __shared__ char sAB[131072];
  int bid = blockIdx.x;
  int nwg = gridDim.x;
  int cpx = nwg >> 3;                       // nwg % 8 == 0 for all launches
  int sbid = (bid & 7) * cpx + (bid >> 3);  // XCD-aware swizzle (bijective)
  int tm = sbid % tiles_m, tn = sbid / tiles_m;
  int m0 = tm * 256, n0 = tn * 256;

  const unsigned short* W = W0; const float* bias = bias0; unsigned short* outB = o0;
  int sel = 0;
  if (MODE == 1) {
    sel = n0 >> 10;
    if (sel == 1) { W = W1; bias = bias1; outB = o1; }
    else if (sel == 2) { W = W2; bias = bias2; outB = o2; }
  }
  int nloc0 = (MODE == 1) ? (n0 & 1023) : n0;

  int t = threadIdx.x, w = t >> 6, l = t & 63;
  int wm = w >> 2, wn = w & 3;              // 2M x 4N waves

  // ---- staging per-thread constants (2 x 16B units per granule) ----
  int u0 = t, u1 = t + 512;
  int lr0 = u0 >> 3, lr1 = u1 >> 3;
  int sl0 = (u0 & 7) ^ (lr0 & 7), sl1 = (u1 & 7) ^ (lr1 & 7);  // inverse-swizzled src slot
  int rA0 = ((lr0 >> 6) << 7) + (lr0 & 63), rA1 = ((lr1 >> 6) << 7) + (lr1 & 63);
  int rB0 = ((lr0 >> 5) << 6) + (lr0 & 31), rB1 = ((lr1 >> 5) << 6) + (lr1 & 31);
  const unsigned short* gA_0 = A + (size_t)(m0 + rA0) * 1024 + sl0 * 8;
  const unsigned short* gA_1 = A + (size_t)(m0 + rA1) * 1024 + sl1 * 8;
  const unsigned short* gB_0 = W + (size_t)(nloc0 + rB0) * 1024 + sl0 * 8;
  const unsigned short* gB_1 = W + (size_t)(nloc0 + rB1) * 1024 + sl1 * 8;

  // ---- reader constants ----
  int aRd = (wm * 64 + (l & 15)) * 128;
  int bRd = (wn * 32 + (l & 15)) * 128;
  int sr0 = (((l >> 4) + 0) ^ (l & 7)) * 16;  // ks=0 swizzled slot
  int sr1 = (((l >> 4) + 4) ^ (l & 7)) * 16;  // ks=1

  f32x4 acc[8][4];
  f32x4 zero = {0.f, 0.f, 0.f, 0.f};
#pragma unroll
  for (int i = 0; i < 8; ++i)
#pragma unroll
    for (int jx = 0; jx < 4; ++jx) acc[i][jx] = zero;
  bf16x8 af[4][2], bf0[2][2], bf1[2][2];

  // ---- prologue: tile0 (4 granules) + tile1 (A-g0, B-g0) ----
  STAGE_A(0, 0, 0); STAGE_B(0, 0, 0); STAGE_A(0, 1, 0); STAGE_B(0, 1, 0);
  STAGE_A(1, 0, 1); STAGE_B(1, 0, 1);
  WAITV4();   // tile0 fully landed (2 granules of tile1 in flight)
  BARX();

  for (int j = 0; j < 8; ++j) {
    int t1 = 2 * j + 1;
    int t2 = (j < 7) ? (2 * j + 2) : 14;  // last iter: re-stage L2-hot tiles
    int t3 = (j < 7) ? (2 * j + 3) : 15;  // (identical bytes -> benign)
    // ph1
    LOAD_A(0, 0); LOAD_B(0, 0, bf0);
    STAGE_A(1, 1, t1);
    BARX(); LGKM0(); P1(); QUAD(0, 0, bf0); P0(); BARX();
    // ph2
    LOAD_B(0, 1, bf1);
    STAGE_B(1, 1, t1);
    BARX(); LGKM0(); P1(); QUAD(0, 1, bf1); P0(); BARX();
    // ph3
    LOAD_A(0, 1);
    STAGE_A(0, 0, t2);
    BARX(); LGKM0(); P1(); QUAD(1, 0, bf0); P0(); BARX();
    // ph4
    STAGE_B(0, 0, t2);
    BARX(); LGKM0(); P1(); QUAD(1, 1, bf1); P0(); WAITV4(); BARX();
    // ph5
    LOAD_A(1, 0); LOAD_B(1, 0, bf0);
    STAGE_A(0, 1, t2);
    BARX(); LGKM0(); P1(); QUAD(0, 0, bf0); P0(); BARX();
    // ph6
    LOAD_B(1, 1, bf1);
    STAGE_B(0, 1, t2);
    BARX(); LGKM0(); P1(); QUAD(0, 1, bf1); P0(); BARX();
    // ph7
    LOAD_A(1, 1);
    STAGE_A(1, 0, t3);
    BARX(); LGKM0(); P1(); QUAD(1, 0, bf0); P0(); BARX();
    // ph8
    STAGE_B(1, 0, t3);
    BARX(); LGKM0(); P1(); QUAD(1, 1, bf1); P0(); WAITV4(); BARX();
  }
  WAITV0();  // no global_load_lds in flight at s_endpgm / during epilogue

  // ---- epilogue ----
#pragma unroll
  for (int mq = 0; mq < 8; ++mq) {
    int grow = m0 + wm * 128 + (mq >> 2) * 64 + (mq & 3) * 16 + ((l >> 4) << 2);
#pragma unroll
    for (int nq = 0; nq < 4; ++nq) {
      int gcol = n0 + wn * 64 + (nq >> 1) * 32 + (nq & 1) * 16 + (l & 15);
      if (MODE == 0) {
        float bb = bias[gcol];
#pragma unroll
        for (int r = 0; r < 4; ++r)
          outF[(size_t)(grow + r) * 1024 + gcol] = acc[mq][nq][r] + bb;
      } else {
        int c = gcol & 1023;
        float bb = bias[c];
#pragma unroll
        for (int r = 0; r < 4; ++r) {
          float v = acc[mq][nq][r] + bb;
          if (sel < 2) v = (v > 0.0f) ? (v + 1.0f) : __expf(v);  // elu(x)+1
          outB[(size_t)(grow + r) * 1024 + c] = f2b(v);
        }
      }
    }
  }
}

// ---------------- per-head transpose: (b,n,h,d) -> [bh][d][n], optional k_sum ----------------
template<int DOSUM>
__global__ __launch_bounds__(256) void transpose_hd(
    const unsigned short* __restrict__ in,   // (16384, 1024)
    unsigned short* __restrict__ out,        // [64][64][4096]
    float* __restrict__ ksum)                // [64][64]
{
  int bid = blockIdx.x;
  int bh = bid >> 6, nt = bid & 63;
  int b = bh >> 4, h = bh & 15;
  int n0 = nt << 6;
  __shared__ unsigned short lds[64][72];
  int t = threadIdx.x;
  int rr = t >> 3, cc = (t & 7) << 3;
#pragma unroll
  for (int p = 0; p < 2; ++p) {
    int n = rr + p * 32;
    const unsigned short* src = in + ((size_t)(b * 4096 + n0 + n) * 1024 + h * 64 + cc);
    *(bf16x8*)&lds[n][cc] = *(const bf16x8*)src;
  }
  __syncthreads();
#pragma unroll
  for (int p = 0; p < 2; ++p) {
    int d = rr + p * 32;
    union { bf16x8 v; unsigned short u[8]; } pk;
    float s = 0.f;
#pragma unroll
    for (int j = 0; j < 8; ++j) {
      unsigned short uv = lds[cc + j][d];
      pk.u[j] = uv;
      if (DOSUM) s += b2f(uv);
    }
    *(bf16x8*)(out + ((size_t)bh * 64 + d) * 4096 + n0 + cc) = pk.v;
    if (DOSUM) {
      s += __shfl_xor(s, 1);
      s += __shfl_xor(s, 2);
      s += __shfl_xor(s, 4);
      if ((t & 7) == 0) atomicAdd(ksum + bh * 64 + d, s);
    }
  }
}

// ---------------- context: ctxT[bh][e][d] = sum_n v[n,e]*k[n,d], split-K over n ----------------
__global__ __launch_bounds__(64) void ctx_gemm(
    const unsigned short* __restrict__ vT,  // [bh][64][4096]
    const unsigned short* __restrict__ kT,  // [bh][64][4096]
    float* __restrict__ ctxT)               // [bh][64][64]
{
  int bid = blockIdx.x;
  int bh = bid >> 3, ch = bid & 7;
  int l = threadIdx.x;
  const unsigned short* aB = vT + ((size_t)bh * 64 + (l & 15)) * 4096 + ch * 512 + ((l >> 4) << 3);
  const unsigned short* bB = kT + ((size_t)bh * 64 + (l & 15)) * 4096 + ch * 512 + ((l >> 4) << 3);
  f32x4 acc[4][4];
  f32x4 zero = {0.f, 0.f, 0.f, 0.f};
#pragma unroll
  for (int i = 0; i < 4; ++i)
#pragma unroll
    for (int j = 0; j < 4; ++j) acc[i][j] = zero;
  for (int ks = 0; ks < 16; ++ks) {
    bf16x8 av[4], bv[4];
#pragma unroll
    for (int mi = 0; mi < 4; ++mi) av[mi] = *(const bf16x8*)(aB + (size_t)mi * 16 * 4096 + ks * 32);
#pragma unroll
    for (int ni = 0; ni < 4; ++ni) bv[ni] = *(const bf16x8*)(bB + (size_t)ni * 16 * 4096 + ks * 32);
#pragma unroll
    for (int mi = 0; mi < 4; ++mi)
#pragma unroll
      for (int ni = 0; ni < 4; ++ni)
        acc[mi][ni] = mfma16(av[mi], bv[ni], acc[mi][ni]);
  }
#pragma unroll
  for (int mi = 0; mi < 4; ++mi)
#pragma unroll
    for (int ni = 0; ni < 4; ++ni)
#pragma unroll
      for (int r = 0; r < 4; ++r) {
        int e = mi * 16 + ((l >> 4) << 2) + r;
        int d = ni * 16 + (l & 15);
        atomicAdd(ctxT + (size_t)bh * 4096 + e * 64 + d, acc[mi][ni][r]);
      }
}

// ---------------- D_inv = 1/(q . k_sum + eps) ----------------
__global__ __launch_bounds__(256) void denom_k(
    const unsigned short* __restrict__ q,
    const float* __restrict__ ksum,
    float* __restrict__ dinv)
{
  int t = threadIdx.x, w = t >> 6, l = t & 63;
  int idx = blockIdx.x * 4 + w;
  int b = idx >> 12;
  int h = l >> 2, part = l & 3;
  const unsigned short* qp = q + (size_t)idx * 1024 + h * 64 + part * 16;
  const float* kp = ksum + ((b << 4) + h) * 64 + part * 16;
  bf16x8 v0 = *(const bf16x8*)qp;
  bf16x8 v1 = *(const bf16x8*)(qp + 8);
  float s = 0.f;
#pragma unroll
  for (int j = 0; j < 8; ++j) s += b2f((unsigned short)v0[j]) * kp[j];
#pragma unroll
  for (int j = 0; j < 8; ++j) s += b2f((unsigned short)v1[j]) * kp[8 + j];
  s += __shfl_xor(s, 1);
  s += __shfl_xor(s, 2);
  if (part == 0) dinv[(size_t)idx * 16 + h] = 1.0f / (s + 1e-6f);
}

// ---------------- att = (q @ ctx) * D_inv, written in-place into q ----------------
__global__ __launch_bounds__(256) void att_gemm(
    unsigned short* __restrict__ q,      // (16384,1024) in/out
    const float* __restrict__ ctxT,      // [bh][e][d]
    const float* __restrict__ dinv)      // [16384][16]
{
  int bid = blockIdx.x;
  int bh = bid & 63, mt = bid >> 6;
  int b = bh >> 4, h = bh & 15;
  int t = threadIdx.x, w = t >> 6, l = t & 63;
  int m0 = mt * 256 + w * 64;

  bf16x8 bfr[2][4];
  const float* cb = ctxT + (size_t)bh * 4096;
#pragma unroll
  for (int ks = 0; ks < 2; ++ks)
#pragma unroll
    for (int ni = 0; ni < 4; ++ni) {
      const float* p = cb + (ni * 16 + (l & 15)) * 64 + ks * 32 + ((l >> 4) << 3);
#pragma unroll
      for (int j = 0; j < 8; ++j) bfr[ks][ni][j] = (short)f2b(p[j]);
    }

  f32x4 acc[4][4];
  f32x4 zero = {0.f, 0.f, 0.f, 0.f};
#pragma unroll
  for (int i = 0; i < 4; ++i)
#pragma unroll
    for (int j = 0; j < 4; ++j) acc[i][j] = zero;

  size_t rowbase = (size_t)(b * 4096 + m0 + (l & 15)) * 1024 + h * 64 + ((l >> 4) << 3);
#pragma unroll
  for (int mi = 0; mi < 4; ++mi) {
#pragma unroll
    for (int ks = 0; ks < 2; ++ks) {
      bf16x8 av = *(const bf16x8*)(q + rowbase + (size_t)mi * 16 * 1024 + ks * 32);
#pragma unroll
      for (int ni = 0; ni < 4; ++ni) acc[mi][ni] = mfma16(av, bfr[ks][ni], acc[mi][ni]);
    }
  }

#pragma unroll
  for (int mi = 0; mi < 4; ++mi)
#pragma unroll
    for (int ni = 0; ni < 4; ++ni) {
      int e = ni * 16 + (l & 15);
#pragma unroll
      for (int r = 0; r < 4; ++r) {
        int npos = m0 + mi * 16 + ((l >> 4) << 2) + r;
        float sc = dinv[(size_t)(b * 4096 + npos) * 16 + h];
        q[(size_t)(b * 4096 + npos) * 1024 + h * 64 + e] = f2b(acc[mi][ni][r] * sc);
      }
    }
}

extern "C" void kernel_launch(void* const* d_in, const int* in_sizes, int n_in,
                              void* d_out, int out_size, void* d_ws, size_t ws_size,
                              hipStream_t stream)
{
  const float* x  = (const float*)d_in[0];
  const float* bq = (const float*)d_in[2];
  const float* bk = (const float*)d_in[4];
  const float* bv = (const float*)d_in[6];
  const float* bo = (const float*)d_in[8];
  const float* Wq = (const float*)d_in[1];
  const float* Wk = (const float*)d_in[3];
  const float* Wv = (const float*)d_in[5];
  const float* Wo = (const float*)d_in[7];
  float* out = (float*)d_out;

  char* ws = (char*)d_ws;
  const size_t SB = (size_t)16384 * 1024 * 2;  // 32 MiB slab
  const size_t NEED = 4 * SB + 4 * (1u << 21) + 2 * (1u << 20) + (1u << 14);
  if (ws_size < NEED) return;  // signature: absmax == max|ref| ~ 6.4e-2

  unsigned short* xb  = (unsigned short*)(ws);           // x bf16; later vT
  unsigned short* qb  = (unsigned short*)(ws + SB);      // q bf16; later att
  unsigned short* kb  = (unsigned short*)(ws + 2 * SB);  // k bf16
  unsigned short* vb  = (unsigned short*)(ws + 3 * SB);  // v bf16; later kT
  unsigned short* wqb = (unsigned short*)(ws + 4 * SB);
  unsigned short* wkb = (unsigned short*)(ws + 4 * SB + (1u << 21));
  unsigned short* wvb = (unsigned short*)(ws + 4 * SB + (2u << 21));
  unsigned short* wob = (unsigned short*)(ws + 4 * SB + (3u << 21));
  float* ctxT = (float*)(ws + 4 * SB + (4u << 21));
  float* dinv = (float*)(ws + 4 * SB + (4u << 21) + (1u << 20));
  float* ksum = (float*)(ws + 4 * SB + (4u << 21) + (2u << 20));

  hipMemsetAsync(ctxT, 0, 64 * 64 * 64 * 4, stream);
  hipMemsetAsync(ksum, 0, 64 * 64 * 4, stream);

  cast_k<<<16384, 256, 0, stream>>>(x, xb, 16777216 / 4);
  cast_k<<<1024, 256, 0, stream>>>(Wq, wqb, 1048576 / 4);
  cast_k<<<1024, 256, 0, stream>>>(Wk, wkb, 1048576 / 4);
  cast_k<<<1024, 256, 0, stream>>>(Wv, wvb, 1048576 / 4);
  cast_k<<<1024, 256, 0, stream>>>(Wo, wob, 1048576 / 4);

  // QKV: (16384 x 1024) @ (3072 x 1024)^T, fused bias + elu+1 on q,k
  gemm256<1><<<768, 512, 0, stream>>>(xb, wqb, wkb, wvb, bq, bk, bv,
                                      nullptr, qb, kb, vb, 64);

  transpose_hd<0><<<4096, 256, 0, stream>>>(vb, xb, nullptr);  // vT -> xb
  transpose_hd<1><<<4096, 256, 0, stream>>>(kb, vb, ksum);     // kT -> vb, k_sum

  ctx_gemm<<<512, 64, 0, stream>>>(xb, vb, ctxT);

  denom_k<<<4096, 256, 0, stream>>>(qb, ksum, dinv);

  att_gemm<<<1024, 256, 0, stream>>>(qb, ctxT, dinv);          // att -> qb (in place)

  // final: att @ Wo^T + bo -> f32 out
  gemm256<0><<<256, 512, 0, stream>>>(qb, wob, nullptr, nullptr, bo, nullptr, nullptr,
                                      out, nullptr, nullptr, nullptr, 64);
}